// Round 12
// baseline (845.533 us; speedup 1.0000x reference)
//
#include <hip/hip_runtime.h>
#include <hip/hip_cooperative_groups.h>
#include <cmath>

namespace cg = cooperative_groups;

#define N_NODES 50000
#define SCAN_NB 196      // ceil(50000/256)
#define NTILES  3125     // 50000 / 16 rows per MFMA wave-tile

typedef float f32x4 __attribute__((ext_vector_type(4)));
typedef short bf16x8 __attribute__((ext_vector_type(8)));

// f32 -> bf16 (round-to-nearest-even)
__device__ __forceinline__ unsigned short f2bf(float f) {
  unsigned int u = __float_as_uint(f);
  u = (u + 0x7fffu + ((u >> 16) & 1u)) >> 16;
  return (unsigned short)u;
}
__device__ __forceinline__ float bf2f(unsigned short h) {
  return __uint_as_float((unsigned int)h << 16);
}
__device__ __forceinline__ float bflo(unsigned int q) {
  return __uint_as_float(q << 16);
}
__device__ __forceinline__ float bfhi(unsigned int q) {
  return __uint_as_float(q & 0xffff0000u);
}

// ===========================================================================
// ONE cooperative kernel for the whole pipeline. Rationale: measured
// ~13-15us overhead PER DISPATCH (rounds 5/11 accounting); 11 dispatches
// ~= 150us of the 232us total. Phases separated by grid.sync():
//  P0 init (deg=0, W1/W2 transpose+hi/lo split)
//  P1 hist (localoff[e] = atomicAdd(deg[row]))
//  P2a per-block scan -> incl, partials   P2b offsets -> rowptr
//  P3 scatter edges (no atomics)
//  P4 gemm1: t1(bf16) = emb @ W1, split-precision MFMA, no LDS
//  P5 spmm_relu: h(bf16) = relu(A @ t1)
//  P6 gemm2: t2(bf16) = h @ W2 (W-split MFMA)
//  P7 spmm_softmax: out = softmax(A @ t2)
// __launch_bounds__(256,4): VGPR<=128 -> 4 blocks/CU -> 1024 blocks
// co-resident (LDS is only 1KB). MFMA math identical to round 11.
// ===========================================================================
__global__ __launch_bounds__(256, 4) void mega_kernel(
    const float* __restrict__ emb, const int* __restrict__ arows,
    const int* __restrict__ acols, const float* __restrict__ avals,
    const float* __restrict__ W1, const float* __restrict__ W2,
    float* __restrict__ out,
    unsigned short* __restrict__ t1,   // bufA: t1 [N][128] bf16, later t2 [N][64]
    unsigned int* __restrict__ hq,     // bufB: h [N][64] packed bf16x2
    int2* __restrict__ edges, int* __restrict__ deg, int* __restrict__ rowptr,
    int* __restrict__ partials,
    unsigned short* __restrict__ W1th, unsigned short* __restrict__ W1tl,
    unsigned short* __restrict__ W2th, unsigned short* __restrict__ W2tl,
    int* __restrict__ localoff, int* __restrict__ incl,
    int E) {
  cg::grid_group grid = cg::this_grid();
  __shared__ int s[256];
  const int tid = threadIdx.x;
  const int gtid = blockIdx.x * 256 + tid;
  const int gsz = gridDim.x * 256;
  const int lane = tid & 63;
  const int wid = (blockIdx.x << 2) | (tid >> 6);
  const int nwaves = gridDim.x << 2;

  // ---------------- P0: init ----------------
  for (int i = gtid; i < N_NODES; i += gsz) deg[i] = 0;
  for (int i = gtid; i < 128 * 128; i += gsz) {
    int c = i >> 7, k = i & 127;
    float v = W1[k * 128 + c];
    unsigned short h = f2bf(v);
    W1th[i] = h;
    W1tl[i] = f2bf(v - bf2f(h));
  }
  for (int i = gtid; i < 64 * 128; i += gsz) {
    int c = i >> 7, k = i & 127;
    float v = W2[k * 64 + c];
    unsigned short h = f2bf(v);
    W2th[i] = h;
    W2tl[i] = f2bf(v - bf2f(h));
  }
  grid.sync();

  // ---------------- P1: histogram + per-edge local offset ----------------
  for (int e = gtid; e < E; e += gsz)
    localoff[e] = atomicAdd(&deg[arows[e]], 1);
  grid.sync();

  // ---------------- P2a: per-block inclusive scan ----------------
  if (blockIdx.x < SCAN_NB) {
    int i = blockIdx.x * 256 + tid;
    int v = (i < N_NODES) ? deg[i] : 0;
    s[tid] = v;
    __syncthreads();
    for (int o = 1; o < 256; o <<= 1) {
      int t = (tid >= o) ? s[tid - o] : 0;
      __syncthreads();
      s[tid] += t;
      __syncthreads();
    }
    if (i < N_NODES) incl[i] = s[tid];
    if (tid == 255) partials[blockIdx.x] = s[255];
  }
  grid.sync();

  // ---------------- P2b: block offset (sum of prior partials) -> rowptr ----
  if (blockIdx.x < SCAN_NB) {
    s[tid] = (tid < (int)blockIdx.x) ? partials[tid] : 0;
    __syncthreads();
    for (int o = 128; o >= 1; o >>= 1) {
      if (tid < o) s[tid] += s[tid + o];
      __syncthreads();
    }
    int off = s[0];
    int i = blockIdx.x * 256 + tid;
    if (i < N_NODES) rowptr[i] = incl[i] - deg[i] + off;
  }
  if (gtid == 0) rowptr[N_NODES] = E;
  grid.sync();

  // ---------------- P3: scatter edges (row-sorted, no atomics) ----------
  for (int e = gtid; e < E; e += gsz) {
    int p = rowptr[arows[e]] + localoff[e];
    edges[p] = make_int2(acols[e], __float_as_int(avals[e]));
  }
  grid.sync();

  // ---------------- P4: gemm1  t1 = emb @ W1 (split-precision MFMA) -------
  // Wave-tile = 16 rows x 128 cols. A from global f32 (hi/lo split in regs),
  // B from global bf16 (L1/L2-hot). Frag map (m89): A row=lane&15,
  // k=(lane>>4)*8+j; B col=lane&15; D col=lane&15, row=(lane>>4)*4+reg.
  {
    const int r = lane & 15, q = lane >> 4;
    for (int t = wid; t < NTILES; t += nwaves) {
      const float* xr = emb + (size_t)(t * 16 + r) * 128;
      bf16x8 ah[4], al[4];
#pragma unroll
      for (int k = 0; k < 4; ++k) {
        const f32x4* src = reinterpret_cast<const f32x4*>(xr + k * 32 + q * 8);
        f32x4 a0 = src[0], a1 = src[1];
        bf16x8 h8, l8;
#pragma unroll
        for (int j = 0; j < 4; ++j) {
          unsigned short h = f2bf(a0[j]);
          h8[j] = (short)h;
          l8[j] = (short)f2bf(a0[j] - bf2f(h));
        }
#pragma unroll
        for (int j = 0; j < 4; ++j) {
          unsigned short h = f2bf(a1[j]);
          h8[4 + j] = (short)h;
          l8[4 + j] = (short)f2bf(a1[j] - bf2f(h));
        }
        ah[k] = h8;
        al[k] = l8;
      }
      f32x4 acc[8];
#pragma unroll
      for (int n = 0; n < 8; ++n) acc[n] = (f32x4){0.f, 0.f, 0.f, 0.f};
#pragma unroll
      for (int k = 0; k < 4; ++k) {
#pragma unroll
        for (int n = 0; n < 8; ++n) {
          bf16x8 bh = *reinterpret_cast<const bf16x8*>(
              &W1th[(size_t)(n * 16 + r) * 128 + k * 32 + q * 8]);
          bf16x8 bl = *reinterpret_cast<const bf16x8*>(
              &W1tl[(size_t)(n * 16 + r) * 128 + k * 32 + q * 8]);
          acc[n] = __builtin_amdgcn_mfma_f32_16x16x32_bf16(ah[k], bh, acc[n], 0, 0, 0);
          acc[n] = __builtin_amdgcn_mfma_f32_16x16x32_bf16(ah[k], bl, acc[n], 0, 0, 0);
          acc[n] = __builtin_amdgcn_mfma_f32_16x16x32_bf16(al[k], bh, acc[n], 0, 0, 0);
        }
      }
#pragma unroll
      for (int n = 0; n < 8; ++n)
#pragma unroll
        for (int j = 0; j < 4; ++j)
          t1[(size_t)(t * 16 + q * 4 + j) * 128 + n * 16 + r] = f2bf(acc[n][j]);
    }
  }
  grid.sync();

  // ---------------- P5: spmm_relu  h = relu(A @ t1) ----------------------
  {
    const unsigned int* t1q = (const unsigned int*)t1;  // [N][64] packed
    for (int row = wid; row < N_NODES; row += nwaves) {
      const int beg = rowptr[row];
      const int end = rowptr[row + 1];
      float ax = 0.f, ay = 0.f;
      int i = beg;
      for (; i + 8 <= end; i += 8) {
        int2 e0 = edges[i],     e1 = edges[i + 1], e2 = edges[i + 2], e3 = edges[i + 3];
        int2 e4 = edges[i + 4], e5 = edges[i + 5], e6 = edges[i + 6], e7 = edges[i + 7];
        unsigned int q0 = t1q[(size_t)e0.x * 64 + lane];
        unsigned int q1 = t1q[(size_t)e1.x * 64 + lane];
        unsigned int q2 = t1q[(size_t)e2.x * 64 + lane];
        unsigned int q3 = t1q[(size_t)e3.x * 64 + lane];
        unsigned int q4 = t1q[(size_t)e4.x * 64 + lane];
        unsigned int q5 = t1q[(size_t)e5.x * 64 + lane];
        unsigned int q6 = t1q[(size_t)e6.x * 64 + lane];
        unsigned int q7 = t1q[(size_t)e7.x * 64 + lane];
        float w0 = __int_as_float(e0.y), w1 = __int_as_float(e1.y);
        float w2 = __int_as_float(e2.y), w3 = __int_as_float(e3.y);
        float w4 = __int_as_float(e4.y), w5 = __int_as_float(e5.y);
        float w6 = __int_as_float(e6.y), w7 = __int_as_float(e7.y);
        ax += w0 * bflo(q0) + w1 * bflo(q1) + w2 * bflo(q2) + w3 * bflo(q3) +
              w4 * bflo(q4) + w5 * bflo(q5) + w6 * bflo(q6) + w7 * bflo(q7);
        ay += w0 * bfhi(q0) + w1 * bfhi(q1) + w2 * bfhi(q2) + w3 * bfhi(q3) +
              w4 * bfhi(q4) + w5 * bfhi(q5) + w6 * bfhi(q6) + w7 * bfhi(q7);
      }
      for (; i + 2 <= end; i += 2) {
        int2 e0 = edges[i], e1 = edges[i + 1];
        unsigned int q0 = t1q[(size_t)e0.x * 64 + lane];
        unsigned int q1 = t1q[(size_t)e1.x * 64 + lane];
        float w0 = __int_as_float(e0.y), w1 = __int_as_float(e1.y);
        ax += w0 * bflo(q0) + w1 * bflo(q1);
        ay += w0 * bfhi(q0) + w1 * bfhi(q1);
      }
      if (i < end) {
        int2 e = edges[i];
        unsigned int q = t1q[(size_t)e.x * 64 + lane];
        float w = __int_as_float(e.y);
        ax += w * bflo(q);
        ay += w * bfhi(q);
      }
      ax = fmaxf(ax, 0.f);
      ay = fmaxf(ay, 0.f);
      hq[(size_t)row * 64 + lane] =
          (unsigned int)f2bf(ax) | ((unsigned int)f2bf(ay) << 16);
    }
  }
  grid.sync();

  // ---------------- P6: gemm2  t2 = h @ W2 (W-split MFMA) ----------------
  {
    unsigned short* t2 = t1;  // t1 dead after P5; reuse buffer
    const int r = lane & 15, q = lane >> 4;
    for (int t = wid; t < NTILES; t += nwaves) {
      const unsigned int* hr = hq + (size_t)(t * 16 + r) * 64;
      bf16x8 a[4];
#pragma unroll
      for (int k = 0; k < 4; ++k)
        a[k] = *reinterpret_cast<const bf16x8*>(hr + k * 16 + q * 4);
      f32x4 acc[4];
#pragma unroll
      for (int n = 0; n < 4; ++n) acc[n] = (f32x4){0.f, 0.f, 0.f, 0.f};
#pragma unroll
      for (int k = 0; k < 4; ++k) {
#pragma unroll
        for (int n = 0; n < 4; ++n) {
          bf16x8 bh = *reinterpret_cast<const bf16x8*>(
              &W2th[(size_t)(n * 16 + r) * 128 + k * 32 + q * 8]);
          bf16x8 bl = *reinterpret_cast<const bf16x8*>(
              &W2tl[(size_t)(n * 16 + r) * 128 + k * 32 + q * 8]);
          acc[n] = __builtin_amdgcn_mfma_f32_16x16x32_bf16(a[k], bh, acc[n], 0, 0, 0);
          acc[n] = __builtin_amdgcn_mfma_f32_16x16x32_bf16(a[k], bl, acc[n], 0, 0, 0);
        }
      }
#pragma unroll
      for (int n = 0; n < 4; ++n)
#pragma unroll
        for (int j = 0; j < 4; ++j)
          t2[(size_t)(t * 16 + q * 4 + j) * 64 + n * 16 + r] = f2bf(acc[n][j]);
    }
  }
  grid.sync();

  // ---------------- P7: spmm_softmax  out = softmax(A @ t2) --------------
  {
    const unsigned int* t2q = (const unsigned int*)t1;  // [N][32] packed
    const int sub = lane >> 5;
    const int sl = lane & 31;
    for (int row = wid; row < N_NODES; row += nwaves) {
      const int beg = rowptr[row];
      const int end = rowptr[row + 1];
      float ax = 0.f, ay = 0.f;
      int i = beg;
      for (; i + 8 <= end; i += 8) {
        int2 ea = edges[i + sub];
        int2 eb = edges[i + 2 + sub];
        int2 ec = edges[i + 4 + sub];
        int2 ed = edges[i + 6 + sub];
        unsigned int qa = t2q[(size_t)ea.x * 32 + sl];
        unsigned int qb = t2q[(size_t)eb.x * 32 + sl];
        unsigned int qc = t2q[(size_t)ec.x * 32 + sl];
        unsigned int qd = t2q[(size_t)ed.x * 32 + sl];
        float va = __int_as_float(ea.y), vb = __int_as_float(eb.y);
        float vc = __int_as_float(ec.y), vd = __int_as_float(ed.y);
        ax += va * bflo(qa) + vb * bflo(qb) + vc * bflo(qc) + vd * bflo(qd);
        ay += va * bfhi(qa) + vb * bfhi(qb) + vc * bfhi(qc) + vd * bfhi(qd);
      }
      for (; i < end; i += 2) {
        int j = i + sub;
        bool ok = j < end;
        int2 e = edges[ok ? j : end - 1];
        float v = ok ? __int_as_float(e.y) : 0.f;
        unsigned int q = t2q[(size_t)e.x * 32 + sl];
        ax += v * bflo(q);
        ay += v * bfhi(q);
      }
      ax += __shfl_xor(ax, 32);
      ay += __shfl_xor(ay, 32);
      float m = fmaxf(ax, ay);
      for (int o = 16; o >= 1; o >>= 1) m = fmaxf(m, __shfl_xor(m, o));
      float ex = expf(ax - m), ey = expf(ay - m);
      float ssum = ex + ey;
      for (int o = 16; o >= 1; o >>= 1) ssum += __shfl_xor(ssum, o);
      if (sub == 0)
        reinterpret_cast<float2*>(out)[(size_t)row * 32 + sl] =
            make_float2(ex / ssum, ey / ssum);
    }
  }
}

extern "C" void kernel_launch(void* const* d_in, const int* in_sizes, int n_in,
                              void* d_out, int out_size, void* d_ws, size_t ws_size,
                              hipStream_t stream) {
  const float* emb   = (const float*)d_in[0];
  const int*   arows = (const int*)d_in[1];
  const int*   acols = (const int*)d_in[2];
  const float* avals = (const float*)d_in[3];
  const float* W1    = (const float*)d_in[4];
  const float* W2    = (const float*)d_in[5];
  float* out = (float*)d_out;
  int E = in_sizes[1];

  // ---- workspace layout ----
  const size_t hbytes = (size_t)N_NODES * 128 * sizeof(float);  // 25.6 MB
  char* p = (char*)d_ws;
  unsigned short* t1 = (unsigned short*)p; p += hbytes;   // t1/t2 (bf16)
  unsigned int*   hq = (unsigned int*)p;   p += hbytes;   // h (bf16) / localoff
  int2* edges  = (int2*)p; p += (size_t)E * sizeof(int2); // 6.4 MB
  int*  deg    = (int*)p;  p += (size_t)N_NODES * sizeof(int);
  int*  rowptr = (int*)p;  p += (size_t)(N_NODES + 1) * sizeof(int);
  int*  partials = (int*)p; p += 256 * sizeof(int);
  unsigned short* W1th = (unsigned short*)p; p += 128 * 128 * 2;
  unsigned short* W1tl = (unsigned short*)p; p += 128 * 128 * 2;
  unsigned short* W2th = (unsigned short*)p; p += 64 * 128 * 2;
  unsigned short* W2tl = (unsigned short*)p; p += 64 * 128 * 2;
  // aliases: scan temps in the (not yet written) edges buffer; per-edge
  // local offsets in the (not yet written) h buffer. Both uses are
  // separated from the overwrite by a grid.sync().
  int* incl     = (int*)edges;
  int* localoff = (int*)hq;

  // co-resident grid: __launch_bounds__(256,4) guarantees 4 blocks/CU; the
  // occupancy query is the authoritative bound (host-side, graph-safe).
  int maxb = 4;
  hipOccupancyMaxActiveBlocksPerMultiprocessor(&maxb, mega_kernel, 256, 0);
  int nb = maxb * 256;        // 256 CUs on MI355X
  if (nb > 1024) nb = 1024;
  if (nb < 256) nb = 256;     // scan needs >=196 blocks

  void* args[] = {(void*)&emb, (void*)&arows, (void*)&acols, (void*)&avals,
                  (void*)&W1, (void*)&W2, (void*)&out,
                  (void*)&t1, (void*)&hq, (void*)&edges, (void*)&deg,
                  (void*)&rowptr, (void*)&partials,
                  (void*)&W1th, (void*)&W1tl, (void*)&W2th, (void*)&W2tl,
                  (void*)&localoff, (void*)&incl, (void*)&E};
  hipLaunchCooperativeKernel((const void*)mega_kernel, dim3(nb), dim3(256),
                             args, 0, stream);
}